// Round 12
// baseline (108.994 us; speedup 1.0000x reference)
//
#include <hip/hip_runtime.h>
#include <hip/hip_bf16.h>
#include <hip/hip_fp16.h>
#include <math.h>
#include <string.h>

typedef _Float16 half8 __attribute__((ext_vector_type(8)));
typedef _Float16 half4 __attribute__((ext_vector_type(4)));
typedef float floatx4 __attribute__((ext_vector_type(4)));
typedef float floatx16 __attribute__((ext_vector_type(16)));

#if defined(__has_builtin) && __has_builtin(__builtin_amdgcn_mfma_f32_16x16x16f16)
#define MFMA_PV(a, b, c) __builtin_amdgcn_mfma_f32_16x16x16f16((a), (b), (c), 0, 0, 0)
#else
__device__ __forceinline__ floatx4 mfma_pv_asm(half4 a, half4 b, floatx4 c) {
  floatx4 d;
  asm volatile("v_mfma_f32_16x16x16_f16 %0, %1, %2, %3"
               : "=v"(d) : "v"(a), "v"(b), "v"(c));
  return d;
}
#define MFMA_PV(a, b, c) mfma_pv_asm((a), (b), (c))
#endif

__device__ __forceinline__ floatx16 MFMA_S1(half4 a, half4 b, floatx16 c) {
#if defined(__has_builtin) && __has_builtin(__builtin_amdgcn_mfma_f32_32x32x8f16)
  return __builtin_amdgcn_mfma_f32_32x32x8f16(a, b, c, 0, 0, 0);
#else
  floatx16 d;
  asm volatile("v_mfma_f32_32x32x8_f16 %0, %1, %2, %3"
               : "=v"(d) : "v"(a), "v"(b), "v"(c));
  return d;
#endif
}

__device__ __forceinline__ floatx16 MFMA_S2(half8 a, half8 b, floatx16 c) {
#if defined(__has_builtin) && __has_builtin(__builtin_amdgcn_mfma_f32_32x32x16_f16)
  return __builtin_amdgcn_mfma_f32_32x32x16_f16(a, b, c, 0, 0, 0);
#else
  floatx16 d;
  asm volatile("v_mfma_f32_32x32x16_f16 %0, %1, %2, %3"
               : "=v"(d) : "v"(a), "v"(b), "v"(c));
  return d;
#endif
}

__device__ __forceinline__ float gelu_exact(float z) {
  return 0.5f * z * (1.0f + erff(z * 0.70710678118654752f));
}
__device__ __forceinline__ unsigned int packh2(float a, float b) {
  __half2 h = __halves2half2(__float2half_rn(a), __float2half_rn(b));
  unsigned int u;
  memcpy(&u, &h, 4);
  return u;
}

// Table GELU, f16 lerp: 4B half2{g0,dg} entries, step 1/64 on [-16,16).
__device__ __forceinline__ _Float16 gelu_tab16(float z, const unsigned int* gt) {
  float tf = __builtin_amdgcn_fmed3f(fmaf(z, 64.f, 1024.f), 0.f, 2047.f);
  float fr = __builtin_amdgcn_fractf(tf);
  unsigned int e = gt[(unsigned int)tf];
  union { unsigned int u; _Float16 h[2]; } cv;
  cv.u = e;
  return (_Float16)(cv.h[0] + (_Float16)fr * cv.h[1]);
}

// ---------------------------------------------------------------------------
// Mega kernel 1: blocks [0,nrel) = SELF-CONTAINED rel (per-block gtab via
// erff + in-thread A1/A2 frag build from w1/b1/w2 -> no prep dependency);
// blocks [nrel, nrel+2048) = LayerNorm rows; [+2048, +3072) = w transposes.
// rel math identical to R11 (verified): stage-1 mfma_32x32x8 -> table GELU
// -> in-lane stage-2 mfma_32x32x16 (A2 K-axis permuted to stage-1 D layout).
// ---------------------------------------------------------------------------
__global__ __launch_bounds__(256) void mega1(
    const float* __restrict__ x, const float* __restrict__ ln_g,
    const float* __restrict__ ln_b, __half* __restrict__ h16,
    const float* __restrict__ w_qkv, const float* __restrict__ w_o,
    __half* __restrict__ wqT, __half* __restrict__ woT,
    const float* __restrict__ coords, const float* __restrict__ vels,
    const float* __restrict__ w1, const float* __restrict__ b1,
    const float* __restrict__ w2, const float* __restrict__ b2,
    __half* __restrict__ rel, int j_base, int jspan, int nrel) {
  __shared__ unsigned int gtab[2048];
  __shared__ float ss[4], qq[4];
  const int t = threadIdx.x;
  const int bid = blockIdx.x;

  if (bid >= nrel) {
    int pb = bid - nrel;
    if (pb < 2048) {
      // ---- LayerNorm row ----
      int row = pb;
      float v = x[(size_t)row * 256 + t];
      float s = v, q = v * v;
#pragma unroll
      for (int o = 32; o > 0; o >>= 1) {
        s += __shfl_xor(s, o);
        q += __shfl_xor(q, o);
      }
      int w = t >> 6, l = t & 63;
      if (l == 0) { ss[w] = s; qq[w] = q; }
      __syncthreads();
      s = ss[0] + ss[1] + ss[2] + ss[3];
      q = qq[0] + qq[1] + qq[2] + qq[3];
      float mu = s * (1.f / 256.f);
      float var = q * (1.f / 256.f) - mu * mu;
      float inv = rsqrtf(var + 1e-5f);
      h16[(size_t)row * 256 + t] =
          __float2half_rn((v - mu) * inv * ln_g[t] + ln_b[t]);
    } else {
      // ---- weight transposes ----
      int bx = pb - 2048;
      if (bx < 768) {
        wqT[(size_t)bx * 256 + t] = __float2half_rn(w_qkv[(size_t)t * 768 + bx]);
      } else {
        int n = bx - 768;
        woT[(size_t)n * 256 + t] = __float2half_rn(w_o[(size_t)t * 256 + n]);
      }
    }
    return;
  }

  // ---- rel block ----
  // per-block gtab (16 erff/thread, one-time)
#pragma unroll
  for (int s = 0; s < 8; s++) {
    int e = t * 8 + s;
    float z0 = -16.f + (float)e * (1.f / 64.f);
    float g0 = gelu_exact(z0);
    float g1 = gelu_exact(z0 + (1.f / 64.f));
    gtab[e] = packh2(g0, g1 - g0);
  }
  const int l = t & 63;
  const int li = l & 31, lh = l >> 5;
  // A1 frags (K=8 stage-1 weights), built in-thread
  uint2 a1u0, a1u1;
  {
    float v0[4], v1[4];
#pragma unroll
    for (int e = 0; e < 4; e++) {
      int k = lh * 4 + e;
      v0[e] = (k < 5) ? w1[k * 64 + li] : ((k == 5) ? b1[li] : 0.f);
      v1[e] = (k < 5) ? w1[k * 64 + 32 + li] : ((k == 5) ? b1[32 + li] : 0.f);
    }
    a1u0 = make_uint2(packh2(v0[0], v0[1]), packh2(v0[2], v0[3]));
    a1u1 = make_uint2(packh2(v1[0], v1[1]), packh2(v1[2], v1[3]));
  }
  // A2 frags, K-axis hidden permutation hid = c*16+(e&3)+8*(e>>2)+4*lh
  uint4 a2u0, a2u1, a2u2, a2u3;
#define BUILD_A2(DST, C)                                                       \
  {                                                                            \
    float v[8];                                                                \
    _Pragma("unroll")                                                          \
    for (int e = 0; e < 8; e++) {                                              \
      int hid = (C) * 16 + (e & 3) + 8 * (e >> 2) + 4 * lh;                    \
      v[e] = (li < 8) ? w2[hid * 8 + li] : 0.f;                                \
    }                                                                          \
    DST = make_uint4(packh2(v[0], v[1]), packh2(v[2], v[3]),                   \
                     packh2(v[4], v[5]), packh2(v[6], v[7]));                  \
  }
  BUILD_A2(a2u0, 0) BUILD_A2(a2u1, 1) BUILD_A2(a2u2, 2) BUILD_A2(a2u3, 3)
#undef BUILD_A2

  const int b = bid / jspan;
  const int j = j_base + (bid - b * jspan);
  const int wv = t >> 6;
  float2 cj = *(const float2*)&coords[(size_t)(b * 1024 + j) * 2];
  float2 vj = *(const float2*)&vels[(size_t)(b * 1024 + j) * 2];
  float b2v0 = b2[4 * lh + 0], b2v1 = b2[4 * lh + 1];
  float b2v2 = b2[4 * lh + 2], b2v3 = b2[4 * lh + 3];
  const size_t hstride = (size_t)jspan * 1024;
  __syncthreads();

  for (int itg = 0; itg < 8; itg++) {
    const int i0 = (wv * 8 + itg) * 32;
    const int i = i0 + li;
    float2 ci = *(const float2*)&coords[(size_t)(b * 1024 + i) * 2];
    float2 vi = *(const float2*)&vels[(size_t)(b * 1024 + i) * 2];
    float dx0 = ci.x - cj.x, dx1 = ci.y - cj.y;
    float dv0 = vi.x - vj.x, dv1 = vi.y - vj.y;
    float dist = sqrtf(dx0 * dx0 + dx1 * dx1);
    half4 bf;
    bf[0] = lh ? (_Float16)dv1 : (_Float16)dx0;
    bf[1] = lh ? (_Float16)1.0f : (_Float16)dx1;
    bf[2] = lh ? (_Float16)0.0f : (_Float16)dist;
    bf[3] = lh ? (_Float16)0.0f : (_Float16)dv0;

    floatx16 zinit = {0.f};
    floatx16 acc = {0.f};
    {
      floatx16 z0 = MFMA_S1(*(half4*)&a1u0, bf, zinit);
      unsigned int u[8] __attribute__((aligned(16)));
#pragma unroll
      for (int q = 0; q < 8; q++) {
        _Float16 ga = gelu_tab16(z0[2 * q], gtab);
        _Float16 gb = gelu_tab16(z0[2 * q + 1], gtab);
        union { unsigned int uu; _Float16 h[2]; } cv;
        cv.h[0] = ga; cv.h[1] = gb;
        u[q] = cv.uu;
      }
      acc = MFMA_S2(*(half8*)&a2u0, *(half8*)&u[0], acc);
      acc = MFMA_S2(*(half8*)&a2u1, *(half8*)&u[4], acc);
    }
    {
      floatx16 z1 = MFMA_S1(*(half4*)&a1u1, bf, zinit);
      unsigned int u[8] __attribute__((aligned(16)));
#pragma unroll
      for (int q = 0; q < 8; q++) {
        _Float16 ga = gelu_tab16(z1[2 * q], gtab);
        _Float16 gb = gelu_tab16(z1[2 * q + 1], gtab);
        union { unsigned int uu; _Float16 h[2]; } cv;
        cv.h[0] = ga; cv.h[1] = gb;
        u[q] = cv.uu;
      }
      acc = MFMA_S2(*(half8*)&a2u2, *(half8*)&u[0], acc);
      acc = MFMA_S2(*(half8*)&a2u3, *(half8*)&u[4], acc);
    }
    size_t base = ((size_t)(b * 8) * jspan + (size_t)(j - j_base)) * 1024 + i;
    rel[base + (size_t)(4 * lh + 0) * hstride] = __float2half_rn(acc[0] + b2v0);
    rel[base + (size_t)(4 * lh + 1) * hstride] = __float2half_rn(acc[1] + b2v1);
    rel[base + (size_t)(4 * lh + 2) * hstride] = __float2half_rn(acc[2] + b2v2);
    rel[base + (size_t)(4 * lh + 3) * hstride] = __float2half_rn(acc[3] + b2v3);
  }
}

// ---------------------------------------------------------------------------
// f16 MFMA GEMM: C[M,N] f32 = A16[M,K] @ BT16[N,K]^T (+ bias). Wave = 16x16
// tile; two independent K-chunk accumulator chains.
// ---------------------------------------------------------------------------
__global__ __launch_bounds__(256) void gemm16(
    const __half* __restrict__ A16, const __half* __restrict__ BT16,
    const float* __restrict__ bias, float* __restrict__ C,
    int ntn, int N, int K) {
  int wave = blockIdx.x * 4 + (threadIdx.x >> 6);
  int mt = wave / ntn, nt = wave - mt * ntn;
  int l = threadIdx.x & 63;
  int lg = l >> 4, li = l & 15;
  int m0 = mt * 16, n0 = nt * 16;
  floatx4 acc0 = {0.f, 0.f, 0.f, 0.f};
  floatx4 acc1 = {0.f, 0.f, 0.f, 0.f};
  const _Float16* ap = (const _Float16*)A16 + (size_t)(m0 + li) * K + 8 * lg;
  const _Float16* bp = (const _Float16*)BT16 + (size_t)(n0 + li) * K + 8 * lg;
  for (int k0 = 0; k0 < K; k0 += 64) {
    half8 a0 = *(const half8*)(ap + k0);
    half8 b0 = *(const half8*)(bp + k0);
    half8 a1 = *(const half8*)(ap + k0 + 32);
    half8 b1 = *(const half8*)(bp + k0 + 32);
    acc0 = __builtin_amdgcn_mfma_f32_16x16x32_f16(a0, b0, acc0, 0, 0, 0);
    acc1 = __builtin_amdgcn_mfma_f32_16x16x32_f16(a1, b1, acc1, 0, 0, 0);
  }
  float bb = bias ? bias[n0 + li] : 0.f;
#pragma unroll
  for (int r = 0; r < 4; r++) {
    C[(size_t)(m0 + 4 * lg + r) * N + n0 + li] = acc0[r] + acc1[r] + bb;
  }
}

// ---------------------------------------------------------------------------
// RoPE + split qkv (2048 x 768 f32) -> q,k,v FP16 in (B,H,N,D); fast trig
// ---------------------------------------------------------------------------
__global__ __launch_bounds__(256) void rope_split(const float* __restrict__ qkv,
                                                  __half* __restrict__ qo,
                                                  __half* __restrict__ ko,
                                                  __half* __restrict__ vo) {
  int row = blockIdx.x;
  int b = row >> 10, n = row & 1023;
  int t = threadIdx.x;
  int hh = t >> 5, d = t & 31;
  const float* base = qkv + (size_t)row * 768;
  float vv = base[512 + t];
  int f = d & 15;
  float inv_freq = exp2f((float)f * -0.8304820237218407f);  // 10000^(-f/16)
  float ang = (float)n * inv_freq;
  float sn, cs;
  __sincosf(ang, &sn, &cs);
  float q1 = base[hh * 32 + f], q2 = base[hh * 32 + f + 16];
  float k1 = base[256 + hh * 32 + f], k2 = base[256 + hh * 32 + f + 16];
  float qr = (d < 16) ? (q1 * cs - q2 * sn) : (q2 * cs + q1 * sn);
  float kr = (d < 16) ? (k1 * cs - k2 * sn) : (k2 * cs + k1 * sn);
  size_t oidx = ((size_t)(b * 8 + hh) * 1024 + n) * 32 + d;
  qo[oidx] = __float2half_rn(qr);
  ko[oidx] = __float2half_rn(kr);
  vo[oidx] = __float2half_rn(vv);
}

// ---------------------------------------------------------------------------
// MFMA flash attention (+ s_setprio around MFMA cluster; waves independent).
// ---------------------------------------------------------------------------
__global__ __launch_bounds__(256) void attn_mfma(
    const __half* __restrict__ qh, const __half* __restrict__ kh,
    const __half* __restrict__ vh, const __half* __restrict__ rel,
    int j_base, int jspan, int js_force,
    float* __restrict__ Opart, float* __restrict__ ml) {
  const int task = blockIdx.x * 4 + (threadIdx.x >> 6);
  int js, it, h, b;
  if (js_force >= 0) {
    js = js_force; it = task & 63; h = (task >> 6) & 7; b = task >> 9;
  } else {
    js = task & 3; it = (task >> 2) & 63; h = (task >> 8) & 7; b = task >> 11;
  }
  const int lane = threadIdx.x & 63;
  const int lg = lane >> 4;
  const int li = lane & 15;
  const int i0 = it * 16;
  const size_t bh = (size_t)(b * 8 + h) * 1024;
  const float scale = 0.17677669529663687f;

  const half8 qf = *(const half8*)((const _Float16*)qh + (bh + i0 + li) * 32 + 8 * lg);

  floatx4 accLo = {0.f, 0.f, 0.f, 0.f};
  floatx4 accHi = {0.f, 0.f, 0.f, 0.f};
  float m_run = -3.0e38f, l_run = 0.f;

  for (int jt = js * 256; jt < js * 256 + 256; jt += 16) {
    half8 kf = *(const half8*)((const _Float16*)kh + (bh + jt + li) * 32 + 8 * lg);
    floatx4 zero = {0.f, 0.f, 0.f, 0.f};
    __builtin_amdgcn_s_setprio(1);
    floatx4 st = __builtin_amdgcn_mfma_f32_16x16x32_f16(kf, qf, zero, 0, 0, 0);
    __builtin_amdgcn_s_setprio(0);
    const __half* rrow = rel + ((size_t)(b * 8 + h) * jspan + (jt - j_base + 4 * lg)) * 1024 + i0 + li;
    float s0 = fmaf(st[0], scale, __half2float(rrow[0]));
    float s1 = fmaf(st[1], scale, __half2float(rrow[1024]));
    float s2 = fmaf(st[2], scale, __half2float(rrow[2048]));
    float s3 = fmaf(st[3], scale, __half2float(rrow[3072]));
    float tm = fmaxf(fmaxf(s0, s1), fmaxf(s2, s3));
    tm = fmaxf(tm, __shfl_xor(tm, 16));
    tm = fmaxf(tm, __shfl_xor(tm, 32));
    float nm = fmaxf(m_run, tm);
    float fc = __expf(m_run - nm);
    float p0 = __expf(s0 - nm);
    float p1 = __expf(s1 - nm);
    float p2 = __expf(s2 - nm);
    float p3 = __expf(s3 - nm);
    float ts = (p0 + p1) + (p2 + p3);
    ts += __shfl_xor(ts, 16);
    ts += __shfl_xor(ts, 32);
    l_run = l_run * fc + ts;
    m_run = nm;
    float fT0 = __shfl(fc, 4 * lg + 0);
    float fT1 = __shfl(fc, 4 * lg + 1);
    float fT2 = __shfl(fc, 4 * lg + 2);
    float fT3 = __shfl(fc, 4 * lg + 3);
    accLo[0] *= fT0; accHi[0] *= fT0;
    accLo[1] *= fT1; accHi[1] *= fT1;
    accLo[2] *= fT2; accHi[2] *= fT2;
    accLo[3] *= fT3; accHi[3] *= fT3;
    half4 pf;
    pf[0] = (_Float16)p0; pf[1] = (_Float16)p1;
    pf[2] = (_Float16)p2; pf[3] = (_Float16)p3;
    const _Float16* vb = (const _Float16*)vh + (bh + jt + 4 * lg) * 32 + li;
    half4 vf0, vf1;
    vf0[0] = vb[0];  vf0[1] = vb[32]; vf0[2] = vb[64]; vf0[3] = vb[96];
    vf1[0] = vb[16]; vf1[1] = vb[48]; vf1[2] = vb[80]; vf1[3] = vb[112];
    __builtin_amdgcn_s_setprio(1);
    accLo = MFMA_PV(pf, vf0, accLo);
    accHi = MFMA_PV(pf, vf1, accHi);
    __builtin_amdgcn_s_setprio(0);
  }
  size_t orow = (size_t)(b * 4 + js) * 1024 + i0 + 4 * lg;
#pragma unroll
  for (int r = 0; r < 4; r++) {
    float* op = Opart + (orow + r) * 256 + h * 32 + li;
    op[0] = accLo[r];
    op[16] = accHi[r];
  }
  if (lane < 16) {
    ((float2*)ml)[((size_t)(b * 4 + js) * 1024 + i0 + lane) * 8 + h] =
        make_float2(m_run, l_run);
  }
}

// ---------------------------------------------------------------------------
// Combine j-split partials -> attn16. grid = 2048 (one row each), 256 thr.
// ---------------------------------------------------------------------------
__global__ __launch_bounds__(256) void combine_kernel(
    const float* __restrict__ Opart, const float* __restrict__ ml,
    __half* __restrict__ attn16) {
  int row = blockIdx.x;          // b*1024 + i
  int b = row >> 10, i = row & 1023;
  int t = threadIdx.x, hh = t >> 5;
  float2 mls[4];
  float M = -1e30f;
#pragma unroll
  for (int js = 0; js < 4; js++) {
    mls[js] = ((const float2*)ml)[(((size_t)(b * 4 + js) * 1024) + i) * 8 + hh];
    M = fmaxf(M, mls[js].x);
  }
  float L = 0.f, Ov = 0.f;
#pragma unroll
  for (int js = 0; js < 4; js++) {
    float w = __expf(mls[js].x - M);
    L += mls[js].y * w;
    Ov += Opart[(((size_t)(b * 4 + js) * 1024) + i) * 256 + t] * w;
  }
  attn16[(size_t)row * 256 + t] = __float2half_rn(Ov / L);
}

// ---------------------------------------------------------------------------
extern "C" void kernel_launch(void* const* d_in, const int* in_sizes, int n_in,
                              void* d_out, int out_size, void* d_ws, size_t ws_size,
                              hipStream_t stream) {
  const float* x      = (const float*)d_in[0];
  const float* coords = (const float*)d_in[1];
  const float* vels   = (const float*)d_in[2];
  const float* ln_g   = (const float*)d_in[3];
  const float* ln_b   = (const float*)d_in[4];
  const float* w_qkv  = (const float*)d_in[5];
  const float* w_o    = (const float*)d_in[6];
  const float* b_o    = (const float*)d_in[7];
  const float* w1     = (const float*)d_in[8];
  const float* b1     = (const float*)d_in[9];
  const float* w2     = (const float*)d_in[10];
  const float* b2     = (const float*)d_in[11];
  float* out = (float*)d_out;

  // ws layout (bytes):
  //  [0, 8Mi)     Opart f32 (written by attn, after qkv dead)
  //  [2Mi, 8Mi)   qkv f32 (dead after rope)
  //  [8Mi, +~0.5Mi) wqT f16 | woT f16
  //  [9Mi, 10Mi)  h16 (ln out) -> overwritten by qh after qkv gemm
  //  [10Mi,11Mi) kh  [11Mi,12Mi) vh  [12Mi,13Mi) attn16
  //  [13Mi, 45Mi) rel f16 full (chunk fallback: 8Mi)
  char* wsb = (char*)d_ws;
  float* Opart = (float*)wsb;
  float* qkv   = (float*)(wsb + 2097152);
  __half* wqT  = (__half*)(wsb + 8388608);
  __half* woT  = (__half*)(wsb + 8781824);
  __half* h16  = (__half*)(wsb + 9437184);
  __half* qh   = (__half*)(wsb + 9437184);
  __half* kh   = (__half*)(wsb + 10485760);
  __half* vh   = (__half*)(wsb + 11534336);
  __half* attn16 = (__half*)(wsb + 12582912);
  __half* relh = (__half*)(wsb + 13631488);
  float* ml    = (float*)d_out;  // scratch; final gemm fully rewrites d_out

  const size_t full_bytes = 13631488ull + 33554432ull;  // 45 MiB
  if (ws_size >= full_bytes) {
    // K1: rel (2048, self-contained) + LN (2048) + transposes (1024)
    mega1<<<2048 + 3072, 256, 0, stream>>>(x, ln_g, ln_b, h16, w_qkv, w_o,
                                           wqT, woT, coords, vels, w1, b1, w2,
                                           b2, relh, 0, 1024, 2048);
    gemm16<<<1536, 256, 0, stream>>>(h16, wqT, nullptr, qkv, 48, 768, 256);
    rope_split<<<2048, 256, 0, stream>>>(qkv, qh, kh, vh);
    attn_mfma<<<1024, 256, 0, stream>>>(qh, kh, vh, relh, 0, 1024, -1, Opart, ml);
  } else {
    // chunked: first mega1 does rel chunk 0 + LN + transposes
    mega1<<<512 + 3072, 256, 0, stream>>>(x, ln_g, ln_b, h16, w_qkv, w_o,
                                          wqT, woT, coords, vels, w1, b1, w2,
                                          b2, relh, 0, 256, 512);
    gemm16<<<1536, 256, 0, stream>>>(h16, wqT, nullptr, qkv, 48, 768, 256);
    rope_split<<<2048, 256, 0, stream>>>(qkv, qh, kh, vh);
    attn_mfma<<<256, 256, 0, stream>>>(qh, kh, vh, relh, 0, 256, 0, Opart, ml);
    for (int c = 1; c < 4; c++) {
      mega1<<<512, 256, 0, stream>>>(x, ln_g, ln_b, h16, w_qkv, w_o,
                                     wqT, woT, coords, vels, w1, b1, w2,
                                     b2, relh, c * 256, 256, 512);
      attn_mfma<<<256, 256, 0, stream>>>(qh, kh, vh, relh, c * 256, 256, c,
                                         Opart, ml);
    }
  }
  combine_kernel<<<2048, 256, 0, stream>>>(Opart, ml, attn16);
  gemm16<<<512, 256, 0, stream>>>(attn16, woT, b_o, out, 16, 256, 256);
}